// Round 2
// 1143.531 us; speedup vs baseline: 1.0171x; 1.0171x over previous
//
#include <hip/hip_runtime.h>
#include <hip/hip_bf16.h>

typedef short short8 __attribute__((ext_vector_type(8)));
typedef float floatx4 __attribute__((ext_vector_type(4)));

constexpr int Bc = 64, Lc = 2688, Cc = 256, Wc = 42, Sc = 21;
constexpr int Mrows = Bc * Lc;          // 172032
constexpr float QSCALE = 0.17677669529663689f;  // 32^-0.5

#define GLOAD_LDS(g, l) __builtin_amdgcn_global_load_lds( \
    (const __attribute__((address_space(1))) void*)(g),   \
    (__attribute__((address_space(3))) void*)(l), 16, 0, 0)
#define BAR() __builtin_amdgcn_s_barrier()
#define WAITV4() asm volatile("s_waitcnt vmcnt(4)" ::: "memory")
#define WAITV0() asm volatile("s_waitcnt vmcnt(0)" ::: "memory")
#define LGKM0() do { asm volatile("s_waitcnt lgkmcnt(0)" ::: "memory"); \
                     __builtin_amdgcn_sched_barrier(0); } while (0)

// ---------------- weight transpose + cast, 32x32 LDS tiles, both sides coalesced ----------------
__global__ __launch_bounds__(256) void transpose_cast_k(const float* __restrict__ w,
                                                        __hip_bfloat16* __restrict__ o,
                                                        int K, int N) {
  __shared__ float tile[32][33];
  int tx = threadIdx.x & 31, ty = threadIdx.x >> 5;    // ty in 0..7
  int n0 = blockIdx.x * 32, k0 = blockIdx.y * 32;
#pragma unroll
  for (int r = 0; r < 32; r += 8)
    tile[ty + r][tx] = w[(size_t)(k0 + ty + r) * N + n0 + tx];
  __syncthreads();
#pragma unroll
  for (int r = 0; r < 32; r += 8)
    o[(size_t)(n0 + ty + r) * K + k0 + tx] = __float2bfloat16(tile[tx][ty + r]);
}

// ---------------- LayerNorm (+ optional cyclic shift), 1 wave = 1 row ----------------
__global__ __launch_bounds__(256) void ln_k(const float* __restrict__ x, const float* __restrict__ g,
                                            const float* __restrict__ bta, __hip_bfloat16* __restrict__ out,
                                            int roll) {
  int row = blockIdx.x * 4 + (threadIdx.x >> 6);
  int lane = threadIdx.x & 63;
  int bb = row / Lc, rl = row - bb * Lc;
  int sl = rl + roll; if (sl >= Lc) sl -= Lc;
  const float4 v = *(const float4*)(x + ((size_t)bb * Lc + sl) * Cc + lane * 4);
  float s = v.x + v.y + v.z + v.w;
#pragma unroll
  for (int o = 1; o < 64; o <<= 1) s += __shfl_xor(s, o, 64);
  float mean = s * (1.0f / Cc);
  float d0 = v.x - mean, d1 = v.y - mean, d2 = v.z - mean, d3 = v.w - mean;
  float s2 = d0 * d0 + d1 * d1 + d2 * d2 + d3 * d3;
#pragma unroll
  for (int o = 1; o < 64; o <<= 1) s2 += __shfl_xor(s2, o, 64);
  float r = rsqrtf(s2 * (1.0f / Cc) + 1e-5f);
  const float4 gg = *(const float4*)(g + lane * 4);
  const float4 bb4 = *(const float4*)(bta + lane * 4);
  __hip_bfloat16 tmp[4];
  tmp[0] = __float2bfloat16(d0 * r * gg.x + bb4.x);
  tmp[1] = __float2bfloat16(d1 * r * gg.y + bb4.y);
  tmp[2] = __float2bfloat16(d2 * r * gg.z + bb4.z);
  tmp[3] = __float2bfloat16(d3 * r * gg.w + bb4.w);
  *(uint2*)(out + (size_t)row * Cc + lane * 4) = *(uint2*)tmp;
}

// ---------------- bf16 B^T GEMM, 256x256 tile, 8-wave, 8-phase counted-vmcnt pipeline ----------------
// LDS: [2 buf][2 k-half] regions of 256 rows x 32 cols bf16 (16KB each) for A and B = 128 KiB.
// Swizzle (T2): byte offset within region ^= ((off>>8)&3)<<4 — involution, 16B-chunk granular.
//   Write side: global_load_lds dest stays LINEAR; source address pre-swizzled (guide m173/m201).
//   Read side: ds_read_b128 at swizzled offset -> 4 lanes per bank-quad, uniform (conflict-free).
// Pipeline (T3/T4): during tile kt's 4 phases stage tile kt+1's 4 half-tiles.
//   Visibility discipline: own-wave vmcnt(N) BEFORE the barrier, ds_read only AFTER that barrier.
//   Steady state: 4 loads in flight at tile entry; vmcnt(4) at end of phases 1 and 3 retires
//   exactly the 4-load region consumed next. vmcnt(0) only in prologue + peeled tail.
// EPI 0: qkv -> +bias, scale q cols, bf16.  EPI 1: proj -> +bias, reverse-roll residual, fp32.
// EPI 2: fc1 -> +bias, exact GELU, bf16.    EPI 3: fc2 -> +bias, residual add, fp32.
template <int EPI, int N, int K>
__global__ __launch_bounds__(512, 2) void gemm8(const __hip_bfloat16* __restrict__ A,
                                                const __hip_bfloat16* __restrict__ BT,
                                                const float* __restrict__ bias,
                                                const float* __restrict__ aux,
                                                void* __restrict__ outv) {
  constexpr int NT = K / 64;
  constexpr int NBX = N / 256;
  constexpr int NWG = NBX * (Mrows / 256);
  static_assert(NWG % 8 == 0, "xcd swizzle");
  __shared__ __align__(16) __hip_bfloat16 As[32768];
  __shared__ __align__(16) __hip_bfloat16 Bs[32768];

  const int t = threadIdx.x;
  const int wave = t >> 6, lane = t & 63, q = lane >> 4, lr = lane & 15;
  const int wm = (wave >> 2) * 128, wn = (wave & 3) * 64;

  // T1: XCD-aware bijective block swizzle, bx fastest within an XCD chunk
  const int orig = blockIdx.x;
  const int wgid = (orig & 7) * (NWG / 8) + (orig >> 3);
  const int bx = wgid % NBX, by = wgid / NBX;
  const int n0 = bx * 256, m0 = by * 256;

  // per-thread staging source: chunk c lands linearly at LDS byte c*16; fetch the (row,k)
  // that SHOULD live there under the swizzle (inverse = same XOR).
  auto srcoff = [&](int c) {
    int o = c * 16;
    int u = o ^ (((o >> 8) & 3) << 4);
    return (size_t)(u >> 6) * K + (size_t)((u >> 4) & 3) * 8;
  };
  const __hip_bfloat16* sA0 = A + (size_t)m0 * K + srcoff(t);
  const __hip_bfloat16* sA1 = A + (size_t)m0 * K + srcoff(512 + t);
  const __hip_bfloat16* sB0 = BT + (size_t)n0 * K + srcoff(t);
  const __hip_bfloat16* sB1 = BT + (size_t)n0 * K + srcoff(512 + t);

  // swizzled LDS read byte-offsets (per-thread constants)
  int offA[8], offB[4];
#pragma unroll
  for (int i = 0; i < 8; i++) {
    int lin = (wm + i * 16 + lr) * 64 + q * 16;
    offA[i] = lin ^ (((lin >> 8) & 3) << 4);
  }
#pragma unroll
  for (int j = 0; j < 4; j++) {
    int lin = (wn + j * 16 + lr) * 64 + q * 16;
    offB[j] = lin ^ (((lin >> 8) & 3) << 4);
  }

  floatx4 acc[8][4] = {};
  short8 afr[4], bfr[4];

#define STAGE(s0, s1, region, koff) do {            \
    __hip_bfloat16* l_ = (region) + wave * 512;     \
    GLOAD_LDS((s0) + (koff), l_);                   \
    GLOAD_LDS((s1) + (koff), l_ + 4096); } while (0)

#define LDA4(base_, mq_) { \
    const char* Ab_ = (const char*)(base_); \
    _Pragma("unroll") for (int i_ = 0; i_ < 4; i_++) afr[i_] = *(const short8*)(Ab_ + offA[(mq_) * 4 + i_]); }
#define LDB4(base_) { \
    const char* Bb_ = (const char*)(base_); \
    _Pragma("unroll") for (int j_ = 0; j_ < 4; j_++) bfr[j_] = *(const short8*)(Bb_ + offB[j_]); }
#define MFMA16(mq_) \
    __builtin_amdgcn_s_setprio(1); \
    _Pragma("unroll") for (int i_ = 0; i_ < 4; i_++) \
    _Pragma("unroll") for (int j_ = 0; j_ < 4; j_++) \
      acc[(mq_) * 4 + i_][j_] = __builtin_amdgcn_mfma_f32_16x16x32_bf16(afr[i_], bfr[j_], acc[(mq_) * 4 + i_][j_], 0, 0, 0); \
    __builtin_amdgcn_s_setprio(0);

  // prologue: stage tile 0 fully, drain, barrier -> tile 0 globally visible
  STAGE(sA0, sA1, As + 0 * 8192, 0);
  STAGE(sB0, sB1, Bs + 0 * 8192, 0);
  STAGE(sA0, sA1, As + 1 * 8192, 32);
  STAGE(sB0, sB1, Bs + 1 * 8192, 32);
  WAITV0();
  BAR();

  for (int kt = 0; kt < NT - 1; ++kt) {
    const int buf = kt & 1, nbuf = buf ^ 1;
    const int kn = (kt + 1) * 64;
    __hip_bfloat16* A0 = As + (buf * 2 + 0) * 8192;
    __hip_bfloat16* A1 = As + (buf * 2 + 1) * 8192;
    __hip_bfloat16* B0 = Bs + (buf * 2 + 0) * 8192;
    __hip_bfloat16* B1 = Bs + (buf * 2 + 1) * 8192;
    // phase 0: ks=0, rows wm..wm+63; stage next-tile A kh0
    LDA4(A0, 0); LDB4(B0);
    STAGE(sA0, sA1, As + (nbuf * 2 + 0) * 8192, kn);
    BAR(); LGKM0(); MFMA16(0); BAR();
    // phase 1: ks=0, rows wm+64..wm+127 (B frags reused); stage next-tile B kh0
    LDA4(A0, 1);
    STAGE(sB0, sB1, Bs + (nbuf * 2 + 0) * 8192, kn);
    BAR(); LGKM0(); MFMA16(1);
    WAITV4(); BAR();                    // kt's kh1 (4 oldest) landed in ALL waves -> visible
    // phase 2: ks=1; stage next-tile A kh1
    LDA4(A1, 0); LDB4(B1);
    STAGE(sA0, sA1, As + (nbuf * 2 + 1) * 8192, kn + 32);
    BAR(); LGKM0(); MFMA16(0); BAR();
    // phase 3: ks=1; stage next-tile B kh1
    LDA4(A1, 1);
    STAGE(sB0, sB1, Bs + (nbuf * 2 + 1) * 8192, kn + 32);
    BAR(); LGKM0(); MFMA16(1);
    WAITV4(); BAR();                    // next tile's kh0 landed in ALL waves -> visible
  }
  { // peeled last tile: no staging; kh1 still in flight at entry
    const int buf = (NT - 1) & 1;
    __hip_bfloat16* A0 = As + (buf * 2 + 0) * 8192;
    __hip_bfloat16* A1 = As + (buf * 2 + 1) * 8192;
    __hip_bfloat16* B0 = Bs + (buf * 2 + 0) * 8192;
    __hip_bfloat16* B1 = Bs + (buf * 2 + 1) * 8192;
    LDA4(A0, 0); LDB4(B0);
    BAR(); LGKM0(); MFMA16(0); BAR();
    LDA4(A0, 1);
    BAR(); LGKM0(); MFMA16(1);
    WAITV0(); BAR();                    // kh1 landed in ALL waves -> visible
    LDA4(A1, 0); LDB4(B1);
    BAR(); LGKM0(); MFMA16(0); BAR();
    LDA4(A1, 1);
    LGKM0(); MFMA16(1);
  }

  // epilogue: C/D layout row = q*4+rg, col = lr
#pragma unroll
  for (int mf = 0; mf < 8; mf++) {
#pragma unroll
    for (int rg = 0; rg < 4; rg++) {
      int row = m0 + wm + mf * 16 + q * 4 + rg;
      int bb = 0, l = 0;
      if (EPI == 1) {
        bb = row / Lc;
        int rl = row - bb * Lc;
        l = rl + Sc; if (l >= Lc) l -= Lc;
      }
#pragma unroll
      for (int nf = 0; nf < 4; nf++) {
        int col = n0 + wn + nf * 16 + lr;
        float v = acc[mf][nf][rg] + bias[col];
        if (EPI == 0) {
          if (col < 256) v *= QSCALE;
          ((__hip_bfloat16*)outv)[(size_t)row * N + col] = __float2bfloat16(v);
        } else if (EPI == 1) {
          size_t o = ((size_t)bb * Lc + l) * Cc + col;
          ((float*)outv)[o] = aux[o] + v;
        } else if (EPI == 2) {
          v = 0.5f * v * (1.0f + erff(v * 0.70710678118654752f));
          ((__hip_bfloat16*)outv)[(size_t)row * N + col] = __float2bfloat16(v);
        } else {
          size_t o = (size_t)row * Cc + col;
          ((float*)outv)[o] = aux[o] + v;
        }
      }
    }
  }
#undef STAGE
#undef LDA4
#undef LDB4
#undef MFMA16
}

// ---------------- fused window attention: 1 wave = 1 (window, head) ----------------
constexpr int PSTR = 72;                 // LDS row stride (elements)
constexpr int PSZ = 48 * PSTR;           // P: 48 rows x 64 K-cols (42 used)
constexpr int VTSZ = 32 * PSTR;          // V^T: 32 d-rows x 64 j-cols (42 used)

__global__ __launch_bounds__(256) void attn_k(const __hip_bfloat16* __restrict__ qkv,
                                              const float* __restrict__ bias_table,
                                              __hip_bfloat16* __restrict__ o_buf) {
  __shared__ __align__(16) __hip_bfloat16 smem[4 * PSZ + 4 * VTSZ];
  __shared__ float btab[83 * 8];
  const int t = threadIdx.x, wave = t >> 6, lane = t & 63, q = lane >> 4, lr = lane & 15;
  const int win = blockIdx.x >> 1;
  const int h = (blockIdx.x & 1) * 4 + wave;

  for (int i = t; i < (4 * PSZ + 4 * VTSZ) / 8; i += 256) ((uint4*)smem)[i] = uint4{0, 0, 0, 0};
  for (int i = t; i < 83 * 8; i += 256) btab[i] = bias_table[i];
  __syncthreads();

  __hip_bfloat16* Pw = smem + wave * PSZ;
  __hip_bfloat16* VTw = smem + 4 * PSZ + wave * VTSZ;
  const __hip_bfloat16* qbase = qkv + (size_t)win * 42 * 768 + h * 32;
  const __hip_bfloat16* kbase = qbase + 256;
  const __hip_bfloat16* vbase = qbase + 512;

  // stage V^T: 16B coalesced global loads, scalar LDS scatter (transpose)
  for (int c = lane; c < 42 * 4; c += 64) {      // 168 chunks of 8 bf16
    int j = c >> 2, d0 = (c & 3) * 8;
    short8 vv = *(const short8*)(vbase + (size_t)j * 768 + d0);
#pragma unroll
    for (int e = 0; e < 8; e++) ((short*)VTw)[(d0 + e) * PSTR + j] = vv[e];
  }

  // S = Q K^T : fragments straight from global (contiguous 16B in d)
  short8 qf[3], kf[3];
#pragma unroll
  for (int mt = 0; mt < 3; mt++) {
    int i = mt * 16 + lr; if (i > 41) i = 41;
    qf[mt] = *(const short8*)(qbase + (size_t)i * 768 + q * 8);
  }
#pragma unroll
  for (int nt = 0; nt < 3; nt++) {
    int j = nt * 16 + lr; if (j > 41) j = 41;
    kf[nt] = *(const short8*)(kbase + (size_t)j * 768 + q * 8);
  }
  floatx4 sacc[3][3] = {};
#pragma unroll
  for (int mt = 0; mt < 3; mt++)
#pragma unroll
    for (int nt = 0; nt < 3; nt++)
      sacc[mt][nt] = __builtin_amdgcn_mfma_f32_16x16x32_bf16(qf[mt], kf[nt], sacc[mt][nt], 0, 0, 0);

  const bool lastwin = ((win & 63) == 63);
#pragma unroll
  for (int mt = 0; mt < 3; mt++) {
#pragma unroll
    for (int rg = 0; rg < 4; rg++) {
      int row = mt * 16 + q * 4 + rg;
      float sv[3];
      float mx = -1e30f;
#pragma unroll
      for (int nt = 0; nt < 3; nt++) {
        int col = nt * 16 + lr;
        float s = sacc[mt][nt][rg];
        int ri = col - row + 41; ri = ri < 0 ? 0 : (ri > 82 ? 82 : ri);
        s += btab[ri * 8 + h];
        if (lastwin && ((row < 21) != (col < 21))) s -= 100.0f;
        if (col >= 42) s = -1e30f;
        sv[nt] = s;
        mx = fmaxf(mx, s);
      }
#pragma unroll
      for (int o = 1; o < 16; o <<= 1) mx = fmaxf(mx, __shfl_xor(mx, o, 64));
      float sum = 0.0f;
#pragma unroll
      for (int nt = 0; nt < 3; nt++) { float e = __expf(sv[nt] - mx); sv[nt] = e; sum += e; }
#pragma unroll
      for (int o = 1; o < 16; o <<= 1) sum += __shfl_xor(sum, o, 64);
      float inv = 1.0f / sum;
#pragma unroll
      for (int nt = 0; nt < 3; nt++) Pw[row * PSTR + nt * 16 + lr] = __float2bfloat16(sv[nt] * inv);
    }
  }
  __syncthreads();

  floatx4 oacc[3][2] = {};
#pragma unroll
  for (int ks = 0; ks < 2; ks++) {
    short8 pf[3], vf[2];
#pragma unroll
    for (int mt = 0; mt < 3; mt++) pf[mt] = *(const short8*)(Pw + (mt * 16 + lr) * PSTR + ks * 32 + q * 8);
#pragma unroll
    for (int nt = 0; nt < 2; nt++) vf[nt] = *(const short8*)(VTw + (nt * 16 + lr) * PSTR + ks * 32 + q * 8);
#pragma unroll
    for (int mt = 0; mt < 3; mt++)
#pragma unroll
      for (int nt = 0; nt < 2; nt++)
        oacc[mt][nt] = __builtin_amdgcn_mfma_f32_16x16x32_bf16(pf[mt], vf[nt], oacc[mt][nt], 0, 0, 0);
  }
#pragma unroll
  for (int mt = 0; mt < 3; mt++) {
#pragma unroll
    for (int rg = 0; rg < 4; rg++) {
      int row = mt * 16 + q * 4 + rg;
      if (row < 42) {
#pragma unroll
        for (int nt = 0; nt < 2; nt++) {
          int col = nt * 16 + lr;
          o_buf[((size_t)win * 42 + row) * 256 + h * 32 + col] = __float2bfloat16(oacc[mt][nt][rg]);
        }
      }
    }
  }
}

// ---------------- host launch ----------------
extern "C" void kernel_launch(void* const* d_in, const int* in_sizes, int n_in,
                              void* d_out, int out_size, void* d_ws, size_t ws_size,
                              hipStream_t stream) {
  const float* x       = (const float*)d_in[0];
  const float* norm1_g = (const float*)d_in[1];
  const float* norm1_b = (const float*)d_in[2];
  const float* qkv_w   = (const float*)d_in[3];
  const float* qkv_b   = (const float*)d_in[4];
  const float* btab    = (const float*)d_in[5];
  const float* proj_w  = (const float*)d_in[6];
  const float* proj_b  = (const float*)d_in[7];
  const float* norm2_g = (const float*)d_in[8];
  const float* norm2_b = (const float*)d_in[9];
  const float* fc1_w   = (const float*)d_in[10];
  const float* fc1_b   = (const float*)d_in[11];
  const float* fc2_w   = (const float*)d_in[12];
  const float* fc2_b   = (const float*)d_in[13];
  float* out = (float*)d_out;

  char* ws = (char*)d_ws;
  size_t off = 0;
  auto alloc = [&](size_t bytes) { char* p = ws + off; off += (bytes + 255) & ~(size_t)255; return p; };
  __hip_bfloat16* wT_qkv  = (__hip_bfloat16*)alloc((size_t)768 * 256 * 2);
  __hip_bfloat16* wT_proj = (__hip_bfloat16*)alloc((size_t)256 * 256 * 2);
  __hip_bfloat16* wT_fc1  = (__hip_bfloat16*)alloc((size_t)1024 * 256 * 2);
  __hip_bfloat16* wT_fc2  = (__hip_bfloat16*)alloc((size_t)256 * 1024 * 2);
  __hip_bfloat16* buf88   = (__hip_bfloat16*)alloc((size_t)Mrows * 256 * 2);   // h -> o -> m
  __hip_bfloat16* buf352  = (__hip_bfloat16*)alloc((size_t)Mrows * 1024 * 2);  // qkv -> fc1 act

  // 1) weights -> B^T bf16 (coalesced tiles)
  transpose_cast_k<<<dim3(768 / 32, 256 / 32), 256, 0, stream>>>(qkv_w, wT_qkv, 256, 768);
  transpose_cast_k<<<dim3(256 / 32, 256 / 32), 256, 0, stream>>>(proj_w, wT_proj, 256, 256);
  transpose_cast_k<<<dim3(1024 / 32, 256 / 32), 256, 0, stream>>>(fc1_w, wT_fc1, 256, 1024);
  transpose_cast_k<<<dim3(256 / 32, 1024 / 32), 256, 0, stream>>>(fc2_w, wT_fc2, 1024, 256);

  // 2) h = roll(LN1(x), -S) as bf16
  ln_k<<<Mrows / 4, 256, 0, stream>>>(x, norm1_g, norm1_b, buf88, Sc);

  // 3) qkv = h @ qkv_w + b (q pre-scaled), bf16
  gemm8<0, 768, 256><<<dim3(3 * (Mrows / 256)), 512, 0, stream>>>(buf88, wT_qkv, qkv_b, nullptr, buf352);

  // 4) windowed attention -> o
  attn_k<<<(Mrows / Wc) * 2, 256, 0, stream>>>(buf352, btab, buf88);

  // 5) x1 = x + roll(o @ proj_w + b, +S)  -> d_out (fp32)
  gemm8<1, 256, 256><<<dim3(Mrows / 256), 512, 0, stream>>>(buf88, wT_proj, proj_b, x, out);

  // 6) m = LN2(x1) as bf16
  ln_k<<<Mrows / 4, 256, 0, stream>>>(out, norm2_g, norm2_b, buf88, 0);

  // 7) act = gelu(m @ fc1_w + b), bf16
  gemm8<2, 1024, 256><<<dim3(4 * (Mrows / 256)), 512, 0, stream>>>(buf88, wT_fc1, fc1_b, nullptr, buf352);

  // 8) out = x1 + act @ fc2_w + b
  gemm8<3, 256, 1024><<<dim3(Mrows / 256), 512, 0, stream>>>(buf352, wT_fc2, fc2_b, out, out);

  (void)in_sizes; (void)n_in; (void)out_size; (void)ws_size;
}

// Round 3
// 1115.147 us; speedup vs baseline: 1.0430x; 1.0255x over previous
//
#include <hip/hip_runtime.h>
#include <hip/hip_bf16.h>

typedef short short8 __attribute__((ext_vector_type(8)));
typedef float floatx4 __attribute__((ext_vector_type(4)));

constexpr int Bc = 64, Lc = 2688, Cc = 256, Wc = 42, Sc = 21;
constexpr int Mrows = Bc * Lc;          // 172032
constexpr float QSCALE = 0.17677669529663689f;  // 32^-0.5

#define GLOAD_LDS(g, l) __builtin_amdgcn_global_load_lds( \
    (const __attribute__((address_space(1))) void*)(g),   \
    (__attribute__((address_space(3))) void*)(l), 16, 0, 0)
#define BAR() __builtin_amdgcn_s_barrier()
#define WAITV4() asm volatile("s_waitcnt vmcnt(4)" ::: "memory")
#define WAITV0() asm volatile("s_waitcnt vmcnt(0)" ::: "memory")
#define LGKM0() do { asm volatile("s_waitcnt lgkmcnt(0)" ::: "memory"); \
                     __builtin_amdgcn_sched_barrier(0); } while (0)

// ---------------- weight transpose + cast, 32x32 LDS tiles, both sides coalesced ----------------
__global__ __launch_bounds__(256) void transpose_cast_k(const float* __restrict__ w,
                                                        __hip_bfloat16* __restrict__ o,
                                                        int K, int N) {
  __shared__ float tile[32][33];
  int tx = threadIdx.x & 31, ty = threadIdx.x >> 5;    // ty in 0..7
  int n0 = blockIdx.x * 32, k0 = blockIdx.y * 32;
#pragma unroll
  for (int r = 0; r < 32; r += 8)
    tile[ty + r][tx] = w[(size_t)(k0 + ty + r) * N + n0 + tx];
  __syncthreads();
#pragma unroll
  for (int r = 0; r < 32; r += 8)
    o[(size_t)(n0 + ty + r) * K + k0 + tx] = __float2bfloat16(tile[tx][ty + r]);
}

// ---------------- LayerNorm (+ optional cyclic shift), 1 wave = 1 row ----------------
__global__ __launch_bounds__(256) void ln_k(const float* __restrict__ x, const float* __restrict__ g,
                                            const float* __restrict__ bta, __hip_bfloat16* __restrict__ out,
                                            int roll) {
  int row = blockIdx.x * 4 + (threadIdx.x >> 6);
  int lane = threadIdx.x & 63;
  int bb = row / Lc, rl = row - bb * Lc;
  int sl = rl + roll; if (sl >= Lc) sl -= Lc;
  const float4 v = *(const float4*)(x + ((size_t)bb * Lc + sl) * Cc + lane * 4);
  float s = v.x + v.y + v.z + v.w;
#pragma unroll
  for (int o = 1; o < 64; o <<= 1) s += __shfl_xor(s, o, 64);
  float mean = s * (1.0f / Cc);
  float d0 = v.x - mean, d1 = v.y - mean, d2 = v.z - mean, d3 = v.w - mean;
  float s2 = d0 * d0 + d1 * d1 + d2 * d2 + d3 * d3;
#pragma unroll
  for (int o = 1; o < 64; o <<= 1) s2 += __shfl_xor(s2, o, 64);
  float r = rsqrtf(s2 * (1.0f / Cc) + 1e-5f);
  const float4 gg = *(const float4*)(g + lane * 4);
  const float4 bb4 = *(const float4*)(bta + lane * 4);
  __hip_bfloat16 tmp[4];
  tmp[0] = __float2bfloat16(d0 * r * gg.x + bb4.x);
  tmp[1] = __float2bfloat16(d1 * r * gg.y + bb4.y);
  tmp[2] = __float2bfloat16(d2 * r * gg.z + bb4.z);
  tmp[3] = __float2bfloat16(d3 * r * gg.w + bb4.w);
  *(uint2*)(out + (size_t)row * Cc + lane * 4) = *(uint2*)tmp;
}

// ---------------- bf16 B^T GEMM, 256x256 tile, 8-wave, 8-phase counted-vmcnt pipeline ----------------
// K-loop unchanged from the verified round-2 version (see comments there).
// Epilogue (this round): EPI 0/2 route the per-wave 128x64 bf16 tile through a private 16 KB LDS
// slice (XOR-swizzled, conflict-free) to convert 128 scalar 2B stores/thread into 16 dwordx4
// stores/thread. GELU uses the tanh/sigmoid form (~10 VALU ops vs ~30 for erff).
template <int EPI, int N, int K>
__global__ __launch_bounds__(512, 2) void gemm8(const __hip_bfloat16* __restrict__ A,
                                                const __hip_bfloat16* __restrict__ BT,
                                                const float* __restrict__ bias,
                                                const float* __restrict__ aux,
                                                void* __restrict__ outv) {
  constexpr int NT = K / 64;
  constexpr int NBX = N / 256;
  constexpr int NWG = NBX * (Mrows / 256);
  static_assert(NWG % 8 == 0, "xcd swizzle");
  __shared__ __align__(16) __hip_bfloat16 As[32768];
  __shared__ __align__(16) __hip_bfloat16 Bs[32768];

  const int t = threadIdx.x;
  const int wave = t >> 6, lane = t & 63, q = lane >> 4, lr = lane & 15;
  const int wm = (wave >> 2) * 128, wn = (wave & 3) * 64;

  // T1: XCD-aware bijective block swizzle, bx fastest within an XCD chunk
  const int orig = blockIdx.x;
  const int wgid = (orig & 7) * (NWG / 8) + (orig >> 3);
  const int bx = wgid % NBX, by = wgid / NBX;
  const int n0 = bx * 256, m0 = by * 256;

  // per-thread staging source: chunk c lands linearly at LDS byte c*16; fetch the (row,k)
  // that SHOULD live there under the swizzle (inverse = same XOR).
  auto srcoff = [&](int c) {
    int o = c * 16;
    int u = o ^ (((o >> 8) & 3) << 4);
    return (size_t)(u >> 6) * K + (size_t)((u >> 4) & 3) * 8;
  };
  const __hip_bfloat16* sA0 = A + (size_t)m0 * K + srcoff(t);
  const __hip_bfloat16* sA1 = A + (size_t)m0 * K + srcoff(512 + t);
  const __hip_bfloat16* sB0 = BT + (size_t)n0 * K + srcoff(t);
  const __hip_bfloat16* sB1 = BT + (size_t)n0 * K + srcoff(512 + t);

  // swizzled LDS read byte-offsets (per-thread constants)
  int offA[8], offB[4];
#pragma unroll
  for (int i = 0; i < 8; i++) {
    int lin = (wm + i * 16 + lr) * 64 + q * 16;
    offA[i] = lin ^ (((lin >> 8) & 3) << 4);
  }
#pragma unroll
  for (int j = 0; j < 4; j++) {
    int lin = (wn + j * 16 + lr) * 64 + q * 16;
    offB[j] = lin ^ (((lin >> 8) & 3) << 4);
  }

  floatx4 acc[8][4] = {};
  short8 afr[4], bfr[4];

#define STAGE(s0, s1, region, koff) do {            \
    __hip_bfloat16* l_ = (region) + wave * 512;     \
    GLOAD_LDS((s0) + (koff), l_);                   \
    GLOAD_LDS((s1) + (koff), l_ + 4096); } while (0)

#define LDA4(base_, mq_) { \
    const char* Ab_ = (const char*)(base_); \
    _Pragma("unroll") for (int i_ = 0; i_ < 4; i_++) afr[i_] = *(const short8*)(Ab_ + offA[(mq_) * 4 + i_]); }
#define LDB4(base_) { \
    const char* Bb_ = (const char*)(base_); \
    _Pragma("unroll") for (int j_ = 0; j_ < 4; j_++) bfr[j_] = *(const short8*)(Bb_ + offB[j_]); }
#define MFMA16(mq_) \
    __builtin_amdgcn_s_setprio(1); \
    _Pragma("unroll") for (int i_ = 0; i_ < 4; i_++) \
    _Pragma("unroll") for (int j_ = 0; j_ < 4; j_++) \
      acc[(mq_) * 4 + i_][j_] = __builtin_amdgcn_mfma_f32_16x16x32_bf16(afr[i_], bfr[j_], acc[(mq_) * 4 + i_][j_], 0, 0, 0); \
    __builtin_amdgcn_s_setprio(0);

  // prologue: stage tile 0 fully, drain, barrier -> tile 0 globally visible
  STAGE(sA0, sA1, As + 0 * 8192, 0);
  STAGE(sB0, sB1, Bs + 0 * 8192, 0);
  STAGE(sA0, sA1, As + 1 * 8192, 32);
  STAGE(sB0, sB1, Bs + 1 * 8192, 32);
  WAITV0();
  BAR();

  for (int kt = 0; kt < NT - 1; ++kt) {
    const int buf = kt & 1, nbuf = buf ^ 1;
    const int kn = (kt + 1) * 64;
    __hip_bfloat16* A0 = As + (buf * 2 + 0) * 8192;
    __hip_bfloat16* A1 = As + (buf * 2 + 1) * 8192;
    __hip_bfloat16* B0 = Bs + (buf * 2 + 0) * 8192;
    __hip_bfloat16* B1 = Bs + (buf * 2 + 1) * 8192;
    // phase 0: ks=0, rows wm..wm+63; stage next-tile A kh0
    LDA4(A0, 0); LDB4(B0);
    STAGE(sA0, sA1, As + (nbuf * 2 + 0) * 8192, kn);
    BAR(); LGKM0(); MFMA16(0); BAR();
    // phase 1: ks=0, rows wm+64..wm+127 (B frags reused); stage next-tile B kh0
    LDA4(A0, 1);
    STAGE(sB0, sB1, Bs + (nbuf * 2 + 0) * 8192, kn);
    BAR(); LGKM0(); MFMA16(1);
    WAITV4(); BAR();                    // kt's kh1 (4 oldest) landed in ALL waves -> visible
    // phase 2: ks=1; stage next-tile A kh1
    LDA4(A1, 0); LDB4(B1);
    STAGE(sA0, sA1, As + (nbuf * 2 + 1) * 8192, kn + 32);
    BAR(); LGKM0(); MFMA16(0); BAR();
    // phase 3: ks=1; stage next-tile B kh1
    LDA4(A1, 1);
    STAGE(sB0, sB1, Bs + (nbuf * 2 + 1) * 8192, kn + 32);
    BAR(); LGKM0(); MFMA16(1);
    WAITV4(); BAR();                    // next tile's kh0 landed in ALL waves -> visible
  }
  { // peeled last tile: no staging; kh1 still in flight at entry
    const int buf = (NT - 1) & 1;
    __hip_bfloat16* A0 = As + (buf * 2 + 0) * 8192;
    __hip_bfloat16* A1 = As + (buf * 2 + 1) * 8192;
    __hip_bfloat16* B0 = Bs + (buf * 2 + 0) * 8192;
    __hip_bfloat16* B1 = Bs + (buf * 2 + 1) * 8192;
    LDA4(A0, 0); LDB4(B0);
    BAR(); LGKM0(); MFMA16(0); BAR();
    LDA4(A0, 1);
    BAR(); LGKM0(); MFMA16(1);
    WAITV0(); BAR();                    // kh1 landed in ALL waves -> visible
    LDA4(A1, 0); LDB4(B1);
    BAR(); LGKM0(); MFMA16(0); BAR();
    LDA4(A1, 1);
    LGKM0(); MFMA16(1);
  }

  if (EPI == 0 || EPI == 2) {
    // ---- vectorized epilogue: per-wave 16 KB LDS slice, XOR-swizzled transpose ----
    BAR();                               // all waves' K-loop LDS reads complete; As/Bs reusable
    char* Tc = (char*)((wave < 4) ? (As + wave * 8192) : (Bs + (wave - 4) * 8192));
#pragma unroll
    for (int mf = 0; mf < 8; mf++) {
#pragma unroll
      for (int rg = 0; rg < 4; rg++) {
        int row = mf * 16 + q * 4 + rg;              // 0..127 within wave tile
        int sw = ((row >> 2) & 3) << 5;              // distinct per q -> conflict-free writes
#pragma unroll
        for (int nf = 0; nf < 4; nf++) {
          int lcol = nf * 16 + lr;                   // 0..63 within wave tile
          int gcol = n0 + wn + lcol;
          float v = acc[mf][nf][rg] + bias[gcol];
          if (EPI == 0) {
            if (gcol < 256) v *= QSCALE;
          } else {
            // gelu(v) = v * sigmoid(2u), u = 0.79788456*(v + 0.044715 v^3)
            float u = v * (0.7978845608028654f + 0.03567740813630012f * v * v);
            v = v * __builtin_amdgcn_rcpf(1.0f + __expf(-2.0f * u));
          }
          *(__hip_bfloat16*)(Tc + row * 128 + ((lcol * 2) ^ sw)) = __float2bfloat16(v);
        }
      }
    }
    LGKM0();
#pragma unroll
    for (int it = 0; it < 16; it++) {
      int id = it * 64 + lane;
      int row = id >> 3, cg = id & 7;                // 8 rows per iter, 8 chunks per row
      short8 val = *(const short8*)(Tc + row * 128 + ((cg * 16) ^ (((row >> 2) & 3) << 5)));
      *(short8*)((__hip_bfloat16*)outv + (size_t)(m0 + wm + row) * N + (n0 + wn + cg * 8)) = val;
    }
  } else {
    // ---- fp32 residual epilogues (proj / fc2), scalar path ----
#pragma unroll
    for (int mf = 0; mf < 8; mf++) {
#pragma unroll
      for (int rg = 0; rg < 4; rg++) {
        int row = m0 + wm + mf * 16 + q * 4 + rg;
        int bb = 0, l = 0;
        if (EPI == 1) {
          bb = row / Lc;
          int rl = row - bb * Lc;
          l = rl + Sc; if (l >= Lc) l -= Lc;
        }
#pragma unroll
        for (int nf = 0; nf < 4; nf++) {
          int col = n0 + wn + nf * 16 + lr;
          float v = acc[mf][nf][rg] + bias[col];
          if (EPI == 1) {
            size_t o = ((size_t)bb * Lc + l) * Cc + col;
            ((float*)outv)[o] = aux[o] + v;
          } else {
            size_t o = (size_t)row * Cc + col;
            ((float*)outv)[o] = aux[o] + v;
          }
        }
      }
    }
  }
#undef STAGE
#undef LDA4
#undef LDB4
#undef MFMA16
}

// ---------------- fused window attention: 1 wave = 1 (window, head) ----------------
constexpr int PSTR = 72;                 // LDS row stride (elements)
constexpr int PSZ = 48 * PSTR;           // P: 48 rows x 64 K-cols (42 used)
constexpr int VTSZ = 32 * PSTR;          // V^T: 32 d-rows x 64 j-cols (42 used)

__global__ __launch_bounds__(256) void attn_k(const __hip_bfloat16* __restrict__ qkv,
                                              const float* __restrict__ bias_table,
                                              __hip_bfloat16* __restrict__ o_buf) {
  __shared__ __align__(16) __hip_bfloat16 smem[4 * PSZ + 4 * VTSZ];
  __shared__ float btab[83 * 8];
  const int t = threadIdx.x, wave = t >> 6, lane = t & 63, q = lane >> 4, lr = lane & 15;
  const int win = blockIdx.x >> 1;
  const int h = (blockIdx.x & 1) * 4 + wave;

  for (int i = t; i < (4 * PSZ + 4 * VTSZ) / 8; i += 256) ((uint4*)smem)[i] = uint4{0, 0, 0, 0};
  for (int i = t; i < 83 * 8; i += 256) btab[i] = bias_table[i];
  __syncthreads();

  __hip_bfloat16* Pw = smem + wave * PSZ;
  __hip_bfloat16* VTw = smem + 4 * PSZ + wave * VTSZ;
  const __hip_bfloat16* qbase = qkv + (size_t)win * 42 * 768 + h * 32;
  const __hip_bfloat16* kbase = qbase + 256;
  const __hip_bfloat16* vbase = qbase + 512;

  // stage V^T: 16B coalesced global loads, scalar LDS scatter (transpose)
  for (int c = lane; c < 42 * 4; c += 64) {      // 168 chunks of 8 bf16
    int j = c >> 2, d0 = (c & 3) * 8;
    short8 vv = *(const short8*)(vbase + (size_t)j * 768 + d0);
#pragma unroll
    for (int e = 0; e < 8; e++) ((short*)VTw)[(d0 + e) * PSTR + j] = vv[e];
  }

  // S = Q K^T : fragments straight from global (contiguous 16B in d)
  short8 qf[3], kf[3];
#pragma unroll
  for (int mt = 0; mt < 3; mt++) {
    int i = mt * 16 + lr; if (i > 41) i = 41;
    qf[mt] = *(const short8*)(qbase + (size_t)i * 768 + q * 8);
  }
#pragma unroll
  for (int nt = 0; nt < 3; nt++) {
    int j = nt * 16 + lr; if (j > 41) j = 41;
    kf[nt] = *(const short8*)(kbase + (size_t)j * 768 + q * 8);
  }
  floatx4 sacc[3][3] = {};
#pragma unroll
  for (int mt = 0; mt < 3; mt++)
#pragma unroll
    for (int nt = 0; nt < 3; nt++)
      sacc[mt][nt] = __builtin_amdgcn_mfma_f32_16x16x32_bf16(qf[mt], kf[nt], sacc[mt][nt], 0, 0, 0);

  const bool lastwin = ((win & 63) == 63);
#pragma unroll
  for (int mt = 0; mt < 3; mt++) {
#pragma unroll
    for (int rg = 0; rg < 4; rg++) {
      int row = mt * 16 + q * 4 + rg;
      float sv[3];
      float mx = -1e30f;
#pragma unroll
      for (int nt = 0; nt < 3; nt++) {
        int col = nt * 16 + lr;
        float s = sacc[mt][nt][rg];
        int ri = col - row + 41; ri = ri < 0 ? 0 : (ri > 82 ? 82 : ri);
        s += btab[ri * 8 + h];
        if (lastwin && ((row < 21) != (col < 21))) s -= 100.0f;
        if (col >= 42) s = -1e30f;
        sv[nt] = s;
        mx = fmaxf(mx, s);
      }
#pragma unroll
      for (int o = 1; o < 16; o <<= 1) mx = fmaxf(mx, __shfl_xor(mx, o, 64));
      float sum = 0.0f;
#pragma unroll
      for (int nt = 0; nt < 3; nt++) { float e = __expf(sv[nt] - mx); sv[nt] = e; sum += e; }
#pragma unroll
      for (int o = 1; o < 16; o <<= 1) sum += __shfl_xor(sum, o, 64);
      float inv = 1.0f / sum;
#pragma unroll
      for (int nt = 0; nt < 3; nt++) Pw[row * PSTR + nt * 16 + lr] = __float2bfloat16(sv[nt] * inv);
    }
  }
  __syncthreads();

  floatx4 oacc[3][2] = {};
#pragma unroll
  for (int ks = 0; ks < 2; ks++) {
    short8 pf[3], vf[2];
#pragma unroll
    for (int mt = 0; mt < 3; mt++) pf[mt] = *(const short8*)(Pw + (mt * 16 + lr) * PSTR + ks * 32 + q * 8);
#pragma unroll
    for (int nt = 0; nt < 2; nt++) vf[nt] = *(const short8*)(VTw + (nt * 16 + lr) * PSTR + ks * 32 + q * 8);
#pragma unroll
    for (int mt = 0; mt < 3; mt++)
#pragma unroll
      for (int nt = 0; nt < 2; nt++)
        oacc[mt][nt] = __builtin_amdgcn_mfma_f32_16x16x32_bf16(pf[mt], vf[nt], oacc[mt][nt], 0, 0, 0);
  }
#pragma unroll
  for (int mt = 0; mt < 3; mt++) {
#pragma unroll
    for (int rg = 0; rg < 4; rg++) {
      int row = mt * 16 + q * 4 + rg;
      if (row < 42) {
#pragma unroll
        for (int nt = 0; nt < 2; nt++) {
          int col = nt * 16 + lr;
          o_buf[((size_t)win * 42 + row) * 256 + h * 32 + col] = __float2bfloat16(oacc[mt][nt][rg]);
        }
      }
    }
  }
}

// ---------------- host launch ----------------
extern "C" void kernel_launch(void* const* d_in, const int* in_sizes, int n_in,
                              void* d_out, int out_size, void* d_ws, size_t ws_size,
                              hipStream_t stream) {
  const float* x       = (const float*)d_in[0];
  const float* norm1_g = (const float*)d_in[1];
  const float* norm1_b = (const float*)d_in[2];
  const float* qkv_w   = (const float*)d_in[3];
  const float* qkv_b   = (const float*)d_in[4];
  const float* btab    = (const float*)d_in[5];
  const float* proj_w  = (const float*)d_in[6];
  const float* proj_b  = (const float*)d_in[7];
  const float* norm2_g = (const float*)d_in[8];
  const float* norm2_b = (const float*)d_in[9];
  const float* fc1_w   = (const float*)d_in[10];
  const float* fc1_b   = (const float*)d_in[11];
  const float* fc2_w   = (const float*)d_in[12];
  const float* fc2_b   = (const float*)d_in[13];
  float* out = (float*)d_out;

  char* ws = (char*)d_ws;
  size_t off = 0;
  auto alloc = [&](size_t bytes) { char* p = ws + off; off += (bytes + 255) & ~(size_t)255; return p; };
  __hip_bfloat16* wT_qkv  = (__hip_bfloat16*)alloc((size_t)768 * 256 * 2);
  __hip_bfloat16* wT_proj = (__hip_bfloat16*)alloc((size_t)256 * 256 * 2);
  __hip_bfloat16* wT_fc1  = (__hip_bfloat16*)alloc((size_t)1024 * 256 * 2);
  __hip_bfloat16* wT_fc2  = (__hip_bfloat16*)alloc((size_t)256 * 1024 * 2);
  __hip_bfloat16* buf88   = (__hip_bfloat16*)alloc((size_t)Mrows * 256 * 2);   // h -> o -> m
  __hip_bfloat16* buf352  = (__hip_bfloat16*)alloc((size_t)Mrows * 1024 * 2);  // qkv -> fc1 act

  // 1) weights -> B^T bf16 (coalesced tiles)
  transpose_cast_k<<<dim3(768 / 32, 256 / 32), 256, 0, stream>>>(qkv_w, wT_qkv, 256, 768);
  transpose_cast_k<<<dim3(256 / 32, 256 / 32), 256, 0, stream>>>(proj_w, wT_proj, 256, 256);
  transpose_cast_k<<<dim3(1024 / 32, 256 / 32), 256, 0, stream>>>(fc1_w, wT_fc1, 256, 1024);
  transpose_cast_k<<<dim3(256 / 32, 1024 / 32), 256, 0, stream>>>(fc2_w, wT_fc2, 1024, 256);

  // 2) h = roll(LN1(x), -S) as bf16
  ln_k<<<Mrows / 4, 256, 0, stream>>>(x, norm1_g, norm1_b, buf88, Sc);

  // 3) qkv = h @ qkv_w + b (q pre-scaled), bf16
  gemm8<0, 768, 256><<<dim3(3 * (Mrows / 256)), 512, 0, stream>>>(buf88, wT_qkv, qkv_b, nullptr, buf352);

  // 4) windowed attention -> o
  attn_k<<<(Mrows / Wc) * 2, 256, 0, stream>>>(buf352, btab, buf88);

  // 5) x1 = x + roll(o @ proj_w + b, +S)  -> d_out (fp32)
  gemm8<1, 256, 256><<<dim3(Mrows / 256), 512, 0, stream>>>(buf88, wT_proj, proj_b, x, out);

  // 6) m = LN2(x1) as bf16
  ln_k<<<Mrows / 4, 256, 0, stream>>>(out, norm2_g, norm2_b, buf88, 0);

  // 7) act = gelu(m @ fc1_w + b), bf16
  gemm8<2, 1024, 256><<<dim3(4 * (Mrows / 256)), 512, 0, stream>>>(buf88, wT_fc1, fc1_b, nullptr, buf352);

  // 8) out = x1 + act @ fc2_w + b
  gemm8<3, 256, 1024><<<dim3(Mrows / 256), 512, 0, stream>>>(buf352, wT_fc2, fc2_b, out, out);

  (void)in_sizes; (void)n_in; (void)out_size; (void)ws_size;
}